// Round 1
// baseline (209.098 us; speedup 1.0000x reference)
//
#include <hip/hip_runtime.h>

#define TPB 256
#define NT_ 2048
#define NQ_ 257
#define EPT 8   // NT_/TPB

struct Pre {
  double H[256];     // h[i] = p[i+1]-p[i], i=0..255
  double L[256];     // Thomas elimination factors, L[1..254]
  double WINV[256];  // 1/w[i], i=0..254
  double OFF[256];   // off[i] = h[i+1], i=0..253
};

__device__ __forceinline__ double block_sum(double v, double* s, int tid) {
  s[tid] = v; __syncthreads();
  #pragma unroll
  for (int off = TPB / 2; off > 0; off >>= 1) {
    if (tid < off) s[tid] += s[tid + off];
    __syncthreads();
  }
  double r = s[0];
  __syncthreads();
  return r;
}

__device__ __forceinline__ double block_exscan(double v, double* s, int tid) {
  s[tid] = v; __syncthreads();
  #pragma unroll
  for (int off = 1; off < TPB; off <<= 1) {
    double add = (tid >= off) ? s[tid - off] : 0.0;
    __syncthreads();
    s[tid] += add;
    __syncthreads();
  }
  double e = (tid > 0) ? s[tid - 1] : 0.0;
  __syncthreads();
  return e;
}

__global__ void w2_setup(const float* __restrict__ p, Pre* __restrict__ pre) {
  int tid = threadIdx.x;
  if (tid < 256) pre->H[tid] = (double)p[tid + 1] - (double)p[tid];
  __syncthreads();
  if (tid < 254) pre->OFF[tid] = pre->H[tid + 1];
  if (tid == 0) {
    double w = 2.0 * (pre->H[0] + pre->H[1]);
    pre->WINV[0] = 1.0 / w;
    pre->L[0] = 0.0;
    for (int i = 1; i < 255; i++) {
      double om = pre->H[i];              // off[i-1]
      double li = om * pre->WINV[i - 1];
      double diag = 2.0 * (pre->H[i] + pre->H[i + 1]);
      w = diag - li * om;
      pre->L[i] = li;
      pre->WINV[i] = 1.0 / w;
    }
  }
}

__global__ __launch_bounds__(TPB) void w2_main(
    const float* __restrict__ f, const float* __restrict__ obs,
    const float* __restrict__ t, const float* __restrict__ p,
    const Pre* __restrict__ pre, double* __restrict__ row_out) {
  __shared__ double s_arr[NT_];    // cdf, then F
  __shared__ double s_q[NQ_];
  __shared__ double s_M[NQ_];
  __shared__ double s_slope[256];
  __shared__ double s_b[256];
  __shared__ double s_c[256];
  __shared__ double s_d[256];
  __shared__ double s_p[NQ_];
  __shared__ double s_red[TPB];
  __shared__ double s_misc[4];

  const int tid = threadIdx.x;
  const int row = blockIdx.x;
  const int base = tid * EPT;
  const double dx = (double)t[1] - (double)t[0];

  for (int i = tid; i < NQ_; i += TPB) s_p[i] = (double)p[i];

  // ---------- Phase A: obs -> cdf ----------
  const float* orow = obs + (size_t)row * NT_;
  double g[EPT + 1];
  {
    float4 a4 = *reinterpret_cast<const float4*>(orow + base);
    float4 b4 = *reinterpret_cast<const float4*>(orow + base + 4);
    double x;
    x = (double)a4.x; g[0] = x * x;  x = (double)a4.y; g[1] = x * x;
    x = (double)a4.z; g[2] = x * x;  x = (double)a4.w; g[3] = x * x;
    x = (double)b4.x; g[4] = x * x;  x = (double)b4.y; g[5] = x * x;
    x = (double)b4.z; g[6] = x * x;  x = (double)b4.w; g[7] = x * x;
  }
  if (tid < TPB - 1) { double x = (double)orow[base + EPT]; g[EPT] = x * x; }
  else g[EPT] = 0.0;
  if (tid == 0) s_misc[0] = g[0];
  if (tid == TPB - 1) s_misc[1] = g[EPT - 1];
  double sumg = 0.0;
  #pragma unroll
  for (int k = 0; k < EPT; k++) sumg += g[k];
  double totg = block_sum(sumg, s_red, tid);
  double T1 = (totg - 0.5 * (s_misc[0] + s_misc[1])) * dx;
  double sc1 = 0.5 * dx / T1;
  const int emax = (tid == TPB - 1) ? EPT - 1 : EPT;
  double ep = 0.0;
  for (int k = 0; k < emax; k++) ep += (g[k] + g[k + 1]) * sc1;
  double run = block_exscan(ep, s_red, tid);
  if (tid == 0) s_arr[0] = 0.0;
  for (int k = 0; k < emax; k++) {
    run += (g[k] + g[k + 1]) * sc1;
    double c = run;
    if (c > 1.0) c = 1.0;
    if (c < 0.0) c = 0.0;
    s_arr[base + k + 1] = c;
  }
  __syncthreads();

  // ---------- quantiles: q[j] = t[searchsorted(cdf, p[j], 'left') clipped] ----------
  for (int j = tid; j < NQ_; j += TPB) {
    double v = s_p[j];
    int lo = 0, hi = NT_;
    while (lo < hi) {
      int mid = (lo + hi) >> 1;
      if (s_arr[mid] < v) lo = mid + 1; else hi = mid;
    }
    if (lo > NT_ - 1) lo = NT_ - 1;
    s_q[j] = (double)t[lo];
  }
  __syncthreads();

  // ---------- natural cubic spline coefficients ----------
  if (tid < 256) s_slope[tid] = (s_q[tid + 1] - s_q[tid]) / pre->H[tid];
  __syncthreads();
  if (tid < 255) s_M[tid + 1] = 6.0 * (s_slope[tid + 1] - s_slope[tid]);  // rhs
  __syncthreads();
  if (tid == 0) {
    // Thomas: forward elimination then back-substitution (in place in s_M[1..255])
    for (int i = 1; i < 255; i++) s_M[i + 1] -= pre->L[i] * s_M[i];
    s_M[255] *= pre->WINV[254];
    for (int i = 253; i >= 0; i--)
      s_M[i + 1] = (s_M[i + 1] - pre->OFF[i] * s_M[i + 2]) * pre->WINV[i];
    s_M[0] = 0.0;
    s_M[256] = 0.0;
  }
  __syncthreads();
  if (tid < 256) {
    double Mi = s_M[tid], Mi1 = s_M[tid + 1], h = pre->H[tid];
    s_b[tid] = s_slope[tid] - h * (2.0 * Mi + Mi1) / 6.0;
    s_c[tid] = 0.5 * Mi;
    s_d[tid] = (Mi1 - Mi) / (6.0 * h);
  }
  __syncthreads();

  // ---------- Phase B: f -> F (cumtrapz of renorm(f), NOT clipped) ----------
  const float* frow = f + (size_t)row * NT_;
  float fv[EPT];
  double g2[EPT + 1];
  {
    float4 a4 = *reinterpret_cast<const float4*>(frow + base);
    float4 b4 = *reinterpret_cast<const float4*>(frow + base + 4);
    fv[0] = a4.x; fv[1] = a4.y; fv[2] = a4.z; fv[3] = a4.w;
    fv[4] = b4.x; fv[5] = b4.y; fv[6] = b4.z; fv[7] = b4.w;
  }
  #pragma unroll
  for (int k = 0; k < EPT; k++) { double x = (double)fv[k]; g2[k] = x * x; }
  if (tid < TPB - 1) { double x = (double)frow[base + EPT]; g2[EPT] = x * x; }
  else g2[EPT] = 0.0;
  if (tid == 0) s_misc[0] = g2[0];
  if (tid == TPB - 1) s_misc[1] = g2[EPT - 1];
  double sum2 = 0.0;
  #pragma unroll
  for (int k = 0; k < EPT; k++) sum2 += g2[k];
  double tot2 = block_sum(sum2, s_red, tid);
  double T2 = (tot2 - 0.5 * (s_misc[0] + s_misc[1])) * dx;
  double sc2 = 0.5 * dx / T2;
  double ep2 = 0.0;
  for (int k = 0; k < emax; k++) ep2 += (g2[k] + g2[k + 1]) * sc2;
  double run2 = block_exscan(ep2, s_red, tid);
  if (tid == 0) s_arr[0] = 0.0;
  for (int k = 0; k < emax; k++) {
    run2 += (g2[k] + g2[k + 1]) * sc2;
    s_arr[base + k + 1] = run2;
  }
  __syncthreads();

  // ---------- spline eval + trapz((t - Q(F))^2 * f) ----------
  double wsum = 0.0;
  #pragma unroll
  for (int k = 0; k < EPT; k++) {
    int i = base + k;
    double F = s_arr[i];
    int lo = 0, hi = NQ_;
    while (lo < hi) {
      int mid = (lo + hi) >> 1;
      if (s_p[mid] < F) lo = mid + 1; else hi = mid;
    }
    int idx = lo - 1;
    if (idx < 0) idx = 0;
    if (idx > NQ_ - 2) idx = NQ_ - 2;
    double frac = F - s_p[idx];
    double val = s_q[idx] + frac * (s_b[idx] + frac * (s_c[idx] + frac * s_d[idx]));
    double diff = (double)t[i] - val;
    double wv = diff * diff * (double)fv[k];
    if (i == 0) s_misc[2] = wv;
    if (i == NT_ - 1) s_misc[3] = wv;
    wsum += wv;
  }
  double wtot = block_sum(wsum, s_red, tid);
  if (tid == 0) row_out[row] = (wtot - 0.5 * (s_misc[2] + s_misc[3])) * dx;
}

__global__ void w2_reduce(const double* __restrict__ row_out, int ntr,
                          float* __restrict__ out) {
  __shared__ double s[TPB];
  int tid = threadIdx.x;
  double v = 0.0;
  for (int i = tid; i < ntr; i += TPB) v += row_out[i];
  s[tid] = v; __syncthreads();
  for (int off = TPB / 2; off > 0; off >>= 1) {
    if (tid < off) s[tid] += s[tid + off];
    __syncthreads();
  }
  if (tid == 0) out[0] = (float)s[0];
}

extern "C" void kernel_launch(void* const* d_in, const int* in_sizes, int n_in,
                              void* d_out, int out_size, void* d_ws, size_t ws_size,
                              hipStream_t stream) {
  const float* f   = (const float*)d_in[0];
  const float* obs = (const float*)d_in[1];
  const float* t   = (const float*)d_in[2];
  const float* p   = (const float*)d_in[3];
  int nt = in_sizes[2];          // 2048
  int ntr = in_sizes[0] / nt;    // 4096

  Pre* pre = (Pre*)d_ws;
  double* rows = (double*)((char*)d_ws + sizeof(Pre));

  hipLaunchKernelGGL(w2_setup, dim3(1), dim3(256), 0, stream, p, pre);
  hipLaunchKernelGGL(w2_main, dim3(ntr), dim3(TPB), 0, stream,
                     f, obs, t, p, pre, rows);
  hipLaunchKernelGGL(w2_reduce, dim3(1), dim3(TPB), 0, stream,
                     rows, ntr, (float*)d_out);
}

// Round 2
// 139.094 us; speedup vs baseline: 1.5033x; 1.5033x over previous
//
#include <hip/hip_runtime.h>

#define TPB 256
#define NT_ 2048
#define NQ_ 257
#define EPT 8              // NT_/TPB
#define BW 32              // band half-width of T^-1
#define BD (2*BW+1)        // 65
#define BAND_BYTES (BD*256*8)

__device__ __forceinline__ double shfl_up_f64(double x, int off) {
  union { double d; int i[2]; } u; u.d = x;
  u.i[0] = __shfl_up(u.i[0], off, 64);
  u.i[1] = __shfl_up(u.i[1], off, 64);
  return u.d;
}
__device__ __forceinline__ double shfl_down_f64(double x, int off) {
  union { double d; int i[2]; } u; u.d = x;
  u.i[0] = __shfl_down(u.i[0], off, 64);
  u.i[1] = __shfl_down(u.i[1], off, 64);
  return u.d;
}

// ---------------- setup: banded inverse of the (fixed) tridiagonal T ----------------
// T (255x255): diag[i]=2(h[i]+h[i+1]), off[i]=h[i+1]. Stored as
// bandS[d][i] = Tinv[i][i+d-BW] (0 when out of range), d=0..64, i padded to 256.
__global__ void w2_setup(const float* __restrict__ p, double* __restrict__ bandS) {
  __shared__ double sh_h[256];
  __shared__ double sh_L[255];
  __shared__ double sh_winv[255];
  const int tid = threadIdx.x;
  if (tid < 256) sh_h[tid] = (double)p[tid + 1] - (double)p[tid];
  __syncthreads();
  if (tid == 0) {
    sh_L[0] = 0.0;
    double d0 = 2.0 * (sh_h[0] + sh_h[1]);
    sh_winv[0] = 1.0 / d0;
    for (int i = 1; i < 255; i++) {
      double off = sh_h[i];                       // off[i-1]
      double L = off * sh_winv[i - 1];
      double d = 2.0 * (sh_h[i] + sh_h[i + 1]) - L * off;
      sh_L[i] = L;
      sh_winv[i] = 1.0 / d;
    }
  }
  __syncthreads();
  const int j = tid;
  if (j < 255) {
    // forward elimination of e_j: y[i]=0 (i<j), y[j]=1, y[i]=-L[i]*y[i-1]
    double y[BW + 1];
    y[0] = 1.0;
    #pragma unroll
    for (int m = 1; m <= BW; m++) {
      int i = j + m;
      y[m] = (i <= 254) ? (-sh_L[i] * y[m - 1]) : 0.0;
    }
    // back substitution, truncated at |i-j|<=BW
    double xn = 0.0;
    #pragma unroll
    for (int m = BW; m >= 0; m--) {
      int i = j + m;
      double val = 0.0;
      if (i <= 254) {
        double num = y[m] - ((i < 254) ? sh_h[i + 1] * xn : 0.0);
        val = num * sh_winv[i];
        xn = val;
      }
      bandS[(m + BW) * 256 + j] = val;
    }
    #pragma unroll
    for (int m = -1; m >= -BW; m--) {
      int i = j + m;
      double val = 0.0;
      if (i >= 0) {
        val = (-sh_h[i + 1] * xn) * sh_winv[i];
        xn = val;
      }
      bandS[(m + BW) * 256 + j] = val;
    }
  } else {
    for (int mm = 0; mm < BD; mm++) bandS[mm * 256 + j] = 0.0;
  }
}

// ---------------- main: one block per trace ----------------
__global__ __launch_bounds__(TPB, 6) void w2_main(
    const float* __restrict__ f, const float* __restrict__ obs,
    const float* __restrict__ t, const float* __restrict__ p,
    const double* __restrict__ bandS, double* __restrict__ row_out) {
  __shared__ double s_p[NQ_];
  __shared__ double s_q[NQ_];
  __shared__ double s_rhs[255 + 2 * BW];
  __shared__ double s_M[NQ_];
  __shared__ double s_b[256], s_c[256], s_d[256];
  __shared__ double s_w[4];
  __shared__ double s_w2[4];
  __shared__ double s_misc[2];

  const int tid = threadIdx.x;
  const int lane = tid & 63;
  const int wid = tid >> 6;
  const int row = blockIdx.x;
  const int base = tid * EPT;
  const int emax = (tid == TPB - 1) ? EPT - 1 : EPT;

  const double dx = (double)t[1] - (double)t[0];

  for (int i = tid; i < NQ_; i += TPB) s_p[i] = (double)p[i];

  // t[base .. base+8]
  float tl[EPT + 1];
  {
    const float4 a = *reinterpret_cast<const float4*>(t + base);
    const float4 b = *reinterpret_cast<const float4*>(t + base + 4);
    tl[0] = a.x; tl[1] = a.y; tl[2] = a.z; tl[3] = a.w;
    tl[4] = b.x; tl[5] = b.y; tl[6] = b.z; tl[7] = b.w;
  }
  tl[EPT] = (tid < TPB - 1) ? t[base + EPT] : 0.0f;

  // ================= Phase A: obs^2 -> cdf scan -> quantile scatter =================
  const float* orow = obs + (size_t)row * NT_;
  float ov[EPT + 1];
  {
    const float4 a = *reinterpret_cast<const float4*>(orow + base);
    const float4 b = *reinterpret_cast<const float4*>(orow + base + 4);
    ov[0] = a.x; ov[1] = a.y; ov[2] = a.z; ov[3] = a.w;
    ov[4] = b.x; ov[5] = b.y; ov[6] = b.z; ov[7] = b.w;
  }
  ov[EPT] = (tid < TPB - 1) ? orow[base + EPT] : 0.0f;

  double ep = 0.0;
  for (int k = 0; k < emax; k++) {
    double a = (double)ov[k], b = (double)ov[k + 1];
    ep += a * a + b * b;
  }
  // wave inclusive scan
  double v = ep;
  #pragma unroll
  for (int off = 1; off < 64; off <<= 1) {
    double w = shfl_up_f64(v, off);
    if (lane >= off) v += w;
  }
  double excl = shfl_up_f64(v, 1);
  if (lane == 0) excl = 0.0;
  if (lane == 63) s_w[wid] = v;
  __syncthreads();                                   // B1
  double woff = 0.0, tot = 0.0;
  #pragma unroll
  for (int w = 0; w < 4; w++) {
    double sw = s_w[w];
    if (w < wid) woff += sw;
    tot += sw;
  }
  double run = woff + excl;     // exclusive prefix; bit-consistent with neighbor
  double incl = woff + v;       // inclusive; == next thread's run exactly
  double inv = 1.0 / tot;

  // scatter: p[j] in (cdf[i-1], cdf[i]]  ->  q[j] = t[i]
  {
    double cprev = fmin(run * inv, 1.0);
    int jj = (int)(cprev * 256.0);
    if (jj < 0) jj = 0; if (jj > 256) jj = 256;
    while (jj > 0 && s_p[jj - 1] > cprev) jj--;
    while (jj <= 256 && s_p[jj] <= cprev) jj++;
    double r = run;
    for (int k = 0; k < emax; k++) {
      double cu_uns;
      if (k == emax - 1) cu_uns = incl;
      else {
        double a = (double)ov[k], b = (double)ov[k + 1];
        cu_uns = r + (a * a + b * b);
      }
      r = cu_uns;
      double cu = fmin(cu_uns * inv, 1.0);
      double tq = (double)tl[k + 1];
      while (jj <= 256 && s_p[jj] <= cu) { s_q[jj] = tq; jj++; }
    }
    if (tid == 0) s_q[0] = (double)tl[0];            // p[0]=0 -> idx 0
    if (tid == TPB - 1) {                            // p[j] > cdf_max -> idx 2047
      double tq = (double)tl[EPT - 1];
      while (jj <= 256) { s_q[jj] = tq; jj++; }
    }
  }
  __syncthreads();                                   // B2

  // ================= spline rhs + banded solve =================
  // load f row now to hide global latency under the solve
  const float* frow = f + (size_t)row * NT_;
  float fv[EPT + 1];
  {
    const float4 a = *reinterpret_cast<const float4*>(frow + base);
    const float4 b = *reinterpret_cast<const float4*>(frow + base + 4);
    fv[0] = a.x; fv[1] = a.y; fv[2] = a.z; fv[3] = a.w;
    fv[4] = b.x; fv[5] = b.y; fv[6] = b.z; fv[7] = b.w;
  }
  fv[EPT] = (tid < TPB - 1) ? frow[base + EPT] : 0.0f;

  if (tid < 255) {
    double h0 = s_p[tid + 1] - s_p[tid], h1 = s_p[tid + 2] - s_p[tid + 1];
    double sl0 = (s_q[tid + 1] - s_q[tid]) / h0;
    double sl1 = (s_q[tid + 2] - s_q[tid + 1]) / h1;
    s_rhs[BW + tid] = 6.0 * (sl1 - sl0);
  }
  if (tid < BW) s_rhs[tid] = 0.0;
  if (tid >= TPB - BW) s_rhs[tid + 63] = 0.0;        // [BW+255, 319)
  __syncthreads();                                   // B3

  double Mreg = 0.0;
  if (tid < 255) {
    #pragma unroll 13
    for (int dd = 0; dd < BD; dd++)
      Mreg += bandS[dd * 256 + tid] * s_rhs[tid + dd];
  }
  if (tid < 255) s_M[tid + 1] = Mreg;
  if (tid == 0) { s_M[0] = 0.0; s_M[256] = 0.0; }
  __syncthreads();                                   // B4

  {
    double h = s_p[tid + 1] - s_p[tid];
    double Mi = s_M[tid], Mi1 = s_M[tid + 1];
    double sl = (s_q[tid + 1] - s_q[tid]) / h;
    s_b[tid] = sl - h * (2.0 * Mi + Mi1) / 6.0;
    s_c[tid] = 0.5 * Mi;
    s_d[tid] = (Mi1 - Mi) / (6.0 * h);
  }
  __syncthreads();                                   // B5

  // ================= Phase B: f^2 -> F scan -> spline eval + weighted trapz =========
  double ep2 = 0.0;
  for (int k = 0; k < emax; k++) {
    double a = (double)fv[k], b = (double)fv[k + 1];
    ep2 += a * a + b * b;
  }
  double v2 = ep2;
  #pragma unroll
  for (int off = 1; off < 64; off <<= 1) {
    double w = shfl_up_f64(v2, off);
    if (lane >= off) v2 += w;
  }
  double excl2 = shfl_up_f64(v2, 1);
  if (lane == 0) excl2 = 0.0;
  if (lane == 63) s_w2[wid] = v2;
  __syncthreads();                                   // B6
  double woff2 = 0.0, tot2 = 0.0;
  #pragma unroll
  for (int w = 0; w < 4; w++) {
    double sw = s_w2[w];
    if (w < wid) woff2 += sw;
    tot2 += sw;
  }
  double run2 = woff2 + excl2;
  double inv2 = 1.0 / tot2;

  double wsum = 0.0;
  {
    double r2 = run2;
    #pragma unroll
    for (int k = 0; k < EPT; k++) {
      if (k > 0) {
        double a = (double)fv[k - 1], b = (double)fv[k];
        r2 += a * a + b * b;
      }
      double F = r2 * inv2;
      int lo = (int)(F * 256.0) + 1;
      if (lo < 0) lo = 0; if (lo > 256) lo = 256;
      while (lo > 0 && s_p[lo - 1] >= F) lo--;
      while (lo < 257 && s_p[lo] < F) lo++;
      int idx = lo - 1;
      if (idx < 0) idx = 0; if (idx > 255) idx = 255;
      double frac = F - s_p[idx];
      double val = s_q[idx] + frac * (s_b[idx] + frac * (s_c[idx] + frac * s_d[idx]));
      double diff = (double)tl[k] - val;
      double wv = diff * diff * (double)fv[k];
      if (tid == 0 && k == 0) s_misc[0] = wv;
      if (tid == TPB - 1 && k == EPT - 1) s_misc[1] = wv;
      wsum += wv;
    }
  }
  double rv = wsum;
  #pragma unroll
  for (int off = 32; off >= 1; off >>= 1) rv += shfl_down_f64(rv, off);
  if (lane == 0) s_w[wid] = rv;     // s_w free: last read was before B2
  __syncthreads();                                   // B7
  if (tid == 0) {
    double totw = s_w[0] + s_w[1] + s_w[2] + s_w[3];
    row_out[row] = (totw - 0.5 * (s_misc[0] + s_misc[1])) * dx;
  }
}

__global__ void w2_reduce(const double* __restrict__ row_out, int ntr,
                          float* __restrict__ out) {
  __shared__ double s[TPB];
  int tid = threadIdx.x;
  double v = 0.0;
  for (int i = tid; i < ntr; i += TPB) v += row_out[i];
  s[tid] = v; __syncthreads();
  for (int off = TPB / 2; off > 0; off >>= 1) {
    if (tid < off) s[tid] += s[tid + off];
    __syncthreads();
  }
  if (tid == 0) out[0] = (float)s[0];
}

extern "C" void kernel_launch(void* const* d_in, const int* in_sizes, int n_in,
                              void* d_out, int out_size, void* d_ws, size_t ws_size,
                              hipStream_t stream) {
  const float* f   = (const float*)d_in[0];
  const float* obs = (const float*)d_in[1];
  const float* t   = (const float*)d_in[2];
  const float* p   = (const float*)d_in[3];
  int nt = in_sizes[2];          // 2048
  int ntr = in_sizes[0] / nt;    // 4096

  double* bandS = (double*)d_ws;
  double* rows  = (double*)((char*)d_ws + BAND_BYTES);

  hipLaunchKernelGGL(w2_setup, dim3(1), dim3(256), 0, stream, p, bandS);
  hipLaunchKernelGGL(w2_main, dim3(ntr), dim3(TPB), 0, stream,
                     f, obs, t, p, bandS, rows);
  hipLaunchKernelGGL(w2_reduce, dim3(1), dim3(TPB), 0, stream,
                     rows, ntr, (float*)d_out);
}

// Round 3
// 66.802 us; speedup vs baseline: 3.1301x; 2.0822x over previous
//
#include <hip/hip_runtime.h>

#define TPB 256
#define NT_ 2048
#define NQ_ 257
#define EPT 8              // NT_/TPB
#define BW 16              // band half-width of T^-1 (float band)
#define BD (2*BW+1)        // 33
#define BAND_BYTES (BD*256*4)

__device__ __forceinline__ double shfl_down_f64(double x, int off) {
  union { double d; int i[2]; } u; u.d = x;
  u.i[0] = __shfl_down(u.i[0], off, 64);
  u.i[1] = __shfl_down(u.i[1], off, 64);
  return u.d;
}

// ---------------- setup: banded inverse of the (fixed) tridiagonal T ----------------
// T (255x255): diag[i]=2(h[i]+h[i+1]), off[i]=h[i+1]. bandS[d][i] = Tinv[i][i+d-BW].
// Pivots via continued-fraction recurrence with warm start (contraction ~0.072/step).
__global__ void w2_setup(const float* __restrict__ p, float* __restrict__ bandS) {
  __shared__ double sh_h[256];
  __shared__ double sh_L[256];
  __shared__ double sh_winv[256];
  const int tid = threadIdx.x;
  if (tid < 256) sh_h[tid] = (double)p[tid + 1] - (double)p[tid];
  __syncthreads();
  if (tid < 255) {
    int k0 = tid - 26; if (k0 < 0) k0 = 0;
    double w;
    if (k0 == 0) w = 2.0 * (sh_h[0] + sh_h[1]);           // exact w[0]
    else w = 2.0 * (sh_h[k0] + sh_h[k0 + 1]);             // warm guess for w[k0]
    for (int k = k0 + 1; k <= tid; k++) {
      double hk = sh_h[k];
      w = 2.0 * (hk + sh_h[k + 1]) - hk * hk / w;
    }
    sh_winv[tid] = 1.0 / w;
  }
  __syncthreads();
  if (tid < 255) sh_L[tid] = (tid == 0) ? 0.0 : sh_h[tid] * sh_winv[tid - 1];
  __syncthreads();
  const int j = tid;
  if (j < 255) {
    // forward elimination of e_j: y[j]=1, y[i]=-L[i]*y[i-1]
    double y[BW + 1];
    y[0] = 1.0;
    #pragma unroll
    for (int m = 1; m <= BW; m++) {
      int i = j + m;
      y[m] = (i <= 254) ? (-sh_L[i] * y[m - 1]) : 0.0;
    }
    double xn = 0.0;
    #pragma unroll
    for (int m = BW; m >= 0; m--) {
      int i = j + m;
      double val = 0.0;
      if (i <= 254) {
        double num = y[m] - ((i < 254) ? sh_h[i + 1] * xn : 0.0);
        val = num * sh_winv[i];
        xn = val;
      }
      bandS[(m + BW) * 256 + j] = (float)val;
    }
    #pragma unroll
    for (int m = -1; m >= -BW; m--) {
      int i = j + m;
      double val = 0.0;
      if (i >= 0) {
        val = (-sh_h[i + 1] * xn) * sh_winv[i];
        xn = val;
      }
      bandS[(m + BW) * 256 + j] = (float)val;
    }
  } else {
    for (int mm = 0; mm < BD; mm++) bandS[mm * 256 + j] = 0.0f;
  }
}

// ---------------- main: one block per trace, fp32 pipeline ----------------
__global__ __launch_bounds__(TPB, 8) void w2_main(
    const float* __restrict__ f, const float* __restrict__ obs,
    const float* __restrict__ t, const float* __restrict__ p,
    const float* __restrict__ bandS, double* __restrict__ row_out) {
  __shared__ float s_p[NQ_];
  __shared__ float s_q[NQ_];
  __shared__ float s_rhs[255 + 2 * BW];   // 287
  __shared__ float s_M[NQ_];
  __shared__ float s_b[256], s_c[256], s_d[256];
  __shared__ float s_wf[4];
  __shared__ double s_wd[4];
  __shared__ double s_misc[2];

  const int tid = threadIdx.x;
  const int lane = tid & 63;
  const int wid = tid >> 6;
  const int row = blockIdx.x;
  const int base = tid * EPT;
  const int emax = (tid == TPB - 1) ? EPT - 1 : EPT;

  const double dx = (double)t[1] - (double)t[0];

  for (int i = tid; i < NQ_; i += TPB) s_p[i] = p[i];

  float tl[EPT + 1];
  {
    const float4 a = *reinterpret_cast<const float4*>(t + base);
    const float4 b = *reinterpret_cast<const float4*>(t + base + 4);
    tl[0] = a.x; tl[1] = a.y; tl[2] = a.z; tl[3] = a.w;
    tl[4] = b.x; tl[5] = b.y; tl[6] = b.z; tl[7] = b.w;
  }
  tl[EPT] = (tid < TPB - 1) ? t[base + EPT] : 0.0f;

  // ================= Phase A: obs^2 -> cdf scan -> quantile scatter =================
  float sA[EPT];
  float ep = 0.0f;
  {
    const float* orow = obs + (size_t)row * NT_;
    float ov[EPT + 1];
    const float4 a = *reinterpret_cast<const float4*>(orow + base);
    const float4 b = *reinterpret_cast<const float4*>(orow + base + 4);
    ov[0] = a.x; ov[1] = a.y; ov[2] = a.z; ov[3] = a.w;
    ov[4] = b.x; ov[5] = b.y; ov[6] = b.z; ov[7] = b.w;
    ov[EPT] = (tid < TPB - 1) ? orow[base + EPT] : 0.0f;
    for (int k = 0; k < emax; k++) {
      sA[k] = ov[k] * ov[k] + ov[k + 1] * ov[k + 1];
      ep += sA[k];
    }
    if (emax < EPT) sA[EPT - 1] = 0.0f;
  }
  // wave inclusive scan (fp32)
  float v = ep;
  #pragma unroll
  for (int off = 1; off < 64; off <<= 1) {
    float w = __shfl_up(v, off, 64);
    if (lane >= off) v += w;
  }
  float excl = __shfl_up(v, 1, 64);
  if (lane == 0) excl = 0.0f;
  if (lane == 63) s_wf[wid] = v;
  __syncthreads();                                   // B1
  float woff = 0.0f, tot = 0.0f;
  #pragma unroll
  for (int w = 0; w < 4; w++) {
    float sw = s_wf[w];
    if (w < wid) woff += sw;
    tot += sw;
  }
  float run = woff + excl;     // exclusive prefix, bit-consistent with neighbor
  float incl = woff + v;       // inclusive, == next thread's run exactly
  float inv = 1.0f / tot;

  // scatter: first cdf index i with cdf[i] >= p[j]  ->  q[j] = t[i]
  {
    float cprev = fminf(run * inv, 1.0f);
    int jj = (int)(cprev * 256.0f);
    if (jj < 0) jj = 0; if (jj > 256) jj = 256;
    while (jj > 0 && s_p[jj - 1] > cprev) jj--;
    while (jj <= 256 && s_p[jj] <= cprev) jj++;
    float r = run;
    for (int k = 0; k < emax; k++) {
      float cu_uns = (k == emax - 1) ? incl : (r + sA[k]);
      r = cu_uns;
      float cu = fminf(cu_uns * inv, 1.0f);
      float tq = tl[k + 1];
      while (jj <= 256 && s_p[jj] <= cu) { s_q[jj] = tq; jj++; }
    }
    if (tid == 0) s_q[0] = tl[0];                    // p[0]=0 -> cdf idx 0
    if (tid == TPB - 1) {                            // p[j] > cdf_max -> idx NT-1
      float tq = tl[EPT - 1];
      while (jj <= 256) { s_q[jj] = tq; jj++; }
    }
  }
  __syncthreads();                                   // B2

  // ================= spline rhs + banded solve =================
  // load f row now to hide global latency under the solve
  const float* frow = f + (size_t)row * NT_;
  float fv[EPT + 1];
  {
    const float4 a = *reinterpret_cast<const float4*>(frow + base);
    const float4 b = *reinterpret_cast<const float4*>(frow + base + 4);
    fv[0] = a.x; fv[1] = a.y; fv[2] = a.z; fv[3] = a.w;
    fv[4] = b.x; fv[5] = b.y; fv[6] = b.z; fv[7] = b.w;
  }
  fv[EPT] = (tid < TPB - 1) ? frow[base + EPT] : 0.0f;

  if (tid < 255) {
    float h0 = s_p[tid + 1] - s_p[tid], h1 = s_p[tid + 2] - s_p[tid + 1];
    float sl0 = (s_q[tid + 1] - s_q[tid]) / h0;
    float sl1 = (s_q[tid + 2] - s_q[tid + 1]) / h1;
    s_rhs[BW + tid] = 6.0f * (sl1 - sl0);
  }
  if (tid < BW) s_rhs[tid] = 0.0f;
  if (tid >= TPB - BW) s_rhs[tid + (2 * BW - 1)] = 0.0f;  // 271..286
  __syncthreads();                                   // B3

  float Mreg = 0.0f;
  if (tid < 255) {
    #pragma unroll 11
    for (int dd = 0; dd < BD; dd++)
      Mreg += bandS[dd * 256 + tid] * s_rhs[tid + dd];
  }
  if (tid < 255) s_M[tid + 1] = Mreg;
  if (tid == 0) { s_M[0] = 0.0f; s_M[256] = 0.0f; }
  __syncthreads();                                   // B4

  {
    float h = s_p[tid + 1] - s_p[tid];
    float Mi = s_M[tid], Mi1 = s_M[tid + 1];
    float sl = (s_q[tid + 1] - s_q[tid]) / h;
    s_b[tid] = sl - h * (2.0f * Mi + Mi1) * (1.0f / 6.0f);
    s_c[tid] = 0.5f * Mi;
    s_d[tid] = (Mi1 - Mi) / (6.0f * h);
  }
  __syncthreads();                                   // B5

  // ================= Phase B: f^2 -> F scan -> spline eval + weighted trapz =========
  float sB[EPT];
  float ep2 = 0.0f;
  for (int k = 0; k < emax; k++) {
    sB[k] = fv[k] * fv[k] + fv[k + 1] * fv[k + 1];
    ep2 += sB[k];
  }
  if (emax < EPT) sB[EPT - 1] = 0.0f;
  float v2 = ep2;
  #pragma unroll
  for (int off = 1; off < 64; off <<= 1) {
    float w = __shfl_up(v2, off, 64);
    if (lane >= off) v2 += w;
  }
  float excl2 = __shfl_up(v2, 1, 64);
  if (lane == 0) excl2 = 0.0f;
  if (lane == 63) s_wf[wid] = v2;
  __syncthreads();                                   // B6
  float woff2 = 0.0f, tot2 = 0.0f;
  #pragma unroll
  for (int w = 0; w < 4; w++) {
    float sw = s_wf[w];
    if (w < wid) woff2 += sw;
    tot2 += sw;
  }
  float run2 = woff2 + excl2;
  float inv2 = 1.0f / tot2;

  double wsum = 0.0;
  {
    float r2 = run2;
    #pragma unroll
    for (int k = 0; k < EPT; k++) {
      if (k > 0) r2 += sB[k - 1];
      float F = r2 * inv2;
      int lo = (int)(F * 256.0f) + 1;
      if (lo < 0) lo = 0; if (lo > 256) lo = 256;
      while (lo > 0 && s_p[lo - 1] >= F) lo--;
      while (lo < 257 && s_p[lo] < F) lo++;
      int idx = lo - 1;
      if (idx < 0) idx = 0; if (idx > 255) idx = 255;
      float frac = F - s_p[idx];
      float val = s_q[idx] + frac * (s_b[idx] + frac * (s_c[idx] + frac * s_d[idx]));
      float diff = tl[k] - val;
      float wv = diff * diff * fv[k];
      if (tid == 0 && k == 0) s_misc[0] = (double)wv;
      if (tid == TPB - 1 && k == EPT - 1) s_misc[1] = (double)wv;
      wsum += (double)wv;
    }
  }
  double rv = wsum;
  #pragma unroll
  for (int off = 32; off >= 1; off >>= 1) rv += shfl_down_f64(rv, off);
  if (lane == 0) s_wd[wid] = rv;
  __syncthreads();                                   // B7
  if (tid == 0) {
    double totw = s_wd[0] + s_wd[1] + s_wd[2] + s_wd[3];
    row_out[row] = (totw - 0.5 * (s_misc[0] + s_misc[1])) * dx;
  }
}

__global__ void w2_reduce(const double* __restrict__ row_out, int ntr,
                          float* __restrict__ out) {
  __shared__ double s[TPB];
  int tid = threadIdx.x;
  double v = 0.0;
  for (int i = tid; i < ntr; i += TPB) v += row_out[i];
  s[tid] = v; __syncthreads();
  for (int off = TPB / 2; off > 0; off >>= 1) {
    if (tid < off) s[tid] += s[tid + off];
    __syncthreads();
  }
  if (tid == 0) out[0] = (float)s[0];
}

extern "C" void kernel_launch(void* const* d_in, const int* in_sizes, int n_in,
                              void* d_out, int out_size, void* d_ws, size_t ws_size,
                              hipStream_t stream) {
  const float* f   = (const float*)d_in[0];
  const float* obs = (const float*)d_in[1];
  const float* t   = (const float*)d_in[2];
  const float* p   = (const float*)d_in[3];
  int nt = in_sizes[2];          // 2048
  int ntr = in_sizes[0] / nt;    // 4096

  float* bandS = (float*)d_ws;
  double* rows = (double*)((char*)d_ws + BAND_BYTES);

  hipLaunchKernelGGL(w2_setup, dim3(1), dim3(256), 0, stream, p, bandS);
  hipLaunchKernelGGL(w2_main, dim3(ntr), dim3(TPB), 0, stream,
                     f, obs, t, p, bandS, rows);
  hipLaunchKernelGGL(w2_reduce, dim3(1), dim3(TPB), 0, stream,
                     rows, ntr, (float*)d_out);
}

// Round 4
// 54.390 us; speedup vs baseline: 3.8444x; 1.2282x over previous
//
#include <hip/hip_runtime.h>

#define TPB 256
#define NT_ 2048
#define NQ_ 257
#define EPT 8              // NT_/TPB
#define BW 16              // band half-width of T^-1 (float band)
#define BD (2*BW+1)        // 33
#define BAND_BYTES (BD*256*4)

__device__ __forceinline__ double shfl_down_f64(double x, int off) {
  union { double d; int i[2]; } u; u.d = x;
  u.i[0] = __shfl_down(u.i[0], off, 64);
  u.i[1] = __shfl_down(u.i[1], off, 64);
  return u.d;
}

// ---------------- setup: banded inverse of the (fixed) tridiagonal T ----------------
// T (255x255): diag[i]=2(h[i]+h[i+1]), off[i]=h[i+1]. bandS[d][i] = Tinv[i][i+d-BW].
// Pivots via continued-fraction recurrence with warm start (contraction ~0.072/step).
__global__ void w2_setup(const float* __restrict__ p, float* __restrict__ bandS) {
  __shared__ double sh_h[256];
  __shared__ double sh_L[256];
  __shared__ double sh_winv[256];
  const int tid = threadIdx.x;
  if (tid < 256) sh_h[tid] = (double)p[tid + 1] - (double)p[tid];
  __syncthreads();
  if (tid < 255) {
    int k0 = tid - 26; if (k0 < 0) k0 = 0;
    double w;
    if (k0 == 0) w = 2.0 * (sh_h[0] + sh_h[1]);           // exact w[0]
    else w = 2.0 * (sh_h[k0] + sh_h[k0 + 1]);             // warm guess for w[k0]
    for (int k = k0 + 1; k <= tid; k++) {
      double hk = sh_h[k];
      w = 2.0 * (hk + sh_h[k + 1]) - hk * hk / w;
    }
    sh_winv[tid] = 1.0 / w;
  }
  __syncthreads();
  if (tid < 255) sh_L[tid] = (tid == 0) ? 0.0 : sh_h[tid] * sh_winv[tid - 1];
  __syncthreads();
  const int j = tid;
  if (j < 255) {
    // forward elimination of e_j: y[j]=1, y[i]=-L[i]*y[i-1]
    double y[BW + 1];
    y[0] = 1.0;
    #pragma unroll
    for (int m = 1; m <= BW; m++) {
      int i = j + m;
      y[m] = (i <= 254) ? (-sh_L[i] * y[m - 1]) : 0.0;
    }
    double xn = 0.0;
    #pragma unroll
    for (int m = BW; m >= 0; m--) {
      int i = j + m;
      double val = 0.0;
      if (i <= 254) {
        double num = y[m] - ((i < 254) ? sh_h[i + 1] * xn : 0.0);
        val = num * sh_winv[i];
        xn = val;
      }
      bandS[(m + BW) * 256 + j] = (float)val;
    }
    #pragma unroll
    for (int m = -1; m >= -BW; m--) {
      int i = j + m;
      double val = 0.0;
      if (i >= 0) {
        val = (-sh_h[i + 1] * xn) * sh_winv[i];
        xn = val;
      }
      bandS[(m + BW) * 256 + j] = (float)val;
    }
  } else {
    for (int mm = 0; mm < BD; mm++) bandS[mm * 256 + j] = 0.0f;
  }
}

// ---------------- main: one block per trace, fp32 pipeline ----------------
// NOTE: no min-waves arg in __launch_bounds__! (TPB,8) squeezed VGPRs to 32 and
// spilled ~75 MB of scratch to HBM (round-3 WRITE_SIZE). Plain (TPB) -> ~56 VGPR,
// no spill (round-1 evidence: WRITE_SIZE 128 KB).
__global__ __launch_bounds__(TPB) void w2_main(
    const float* __restrict__ f, const float* __restrict__ obs,
    const float* __restrict__ t, const float* __restrict__ p,
    const float* __restrict__ bandS, double* __restrict__ row_out) {
  __shared__ float s_p[NQ_];
  __shared__ float s_q[NQ_];
  __shared__ float s_rhs[255 + 2 * BW];   // 287
  __shared__ float s_M[NQ_];
  __shared__ float s_b[256], s_c[256], s_d[256];
  __shared__ float s_wf[4];
  __shared__ double s_wd[4];
  __shared__ double s_misc[2];

  const int tid = threadIdx.x;
  const int lane = tid & 63;
  const int wid = tid >> 6;
  const int row = blockIdx.x;
  const int base = tid * EPT;
  const int emax = (tid == TPB - 1) ? EPT - 1 : EPT;

  const double dx = (double)t[1] - (double)t[0];

  for (int i = tid; i < NQ_; i += TPB) s_p[i] = p[i];

  float tl[EPT + 1];
  {
    const float4 a = *reinterpret_cast<const float4*>(t + base);
    const float4 b = *reinterpret_cast<const float4*>(t + base + 4);
    tl[0] = a.x; tl[1] = a.y; tl[2] = a.z; tl[3] = a.w;
    tl[4] = b.x; tl[5] = b.y; tl[6] = b.z; tl[7] = b.w;
  }
  tl[EPT] = (tid < TPB - 1) ? t[base + EPT] : 0.0f;

  // ================= Phase A: obs^2 -> cdf scan -> quantile scatter =================
  float sA[EPT];
  float ep = 0.0f;
  {
    const float* orow = obs + (size_t)row * NT_;
    float ov[EPT + 1];
    const float4 a = *reinterpret_cast<const float4*>(orow + base);
    const float4 b = *reinterpret_cast<const float4*>(orow + base + 4);
    ov[0] = a.x; ov[1] = a.y; ov[2] = a.z; ov[3] = a.w;
    ov[4] = b.x; ov[5] = b.y; ov[6] = b.z; ov[7] = b.w;
    ov[EPT] = (tid < TPB - 1) ? orow[base + EPT] : 0.0f;
    for (int k = 0; k < emax; k++) {
      sA[k] = ov[k] * ov[k] + ov[k + 1] * ov[k + 1];
      ep += sA[k];
    }
    if (emax < EPT) sA[EPT - 1] = 0.0f;
  }
  // wave inclusive scan (fp32)
  float v = ep;
  #pragma unroll
  for (int off = 1; off < 64; off <<= 1) {
    float w = __shfl_up(v, off, 64);
    if (lane >= off) v += w;
  }
  float excl = __shfl_up(v, 1, 64);
  if (lane == 0) excl = 0.0f;
  if (lane == 63) s_wf[wid] = v;
  __syncthreads();                                   // B1
  float woff = 0.0f, tot = 0.0f;
  #pragma unroll
  for (int w = 0; w < 4; w++) {
    float sw = s_wf[w];
    if (w < wid) woff += sw;
    tot += sw;
  }
  float run = woff + excl;     // exclusive prefix, bit-consistent with neighbor
  float incl = woff + v;       // inclusive, == next thread's run exactly
  float inv = 1.0f / tot;

  // scatter: first cdf index i with cdf[i] >= p[j]  ->  q[j] = t[i]
  {
    float cprev = fminf(run * inv, 1.0f);
    int jj = (int)(cprev * 256.0f);
    if (jj < 0) jj = 0; if (jj > 256) jj = 256;
    while (jj > 0 && s_p[jj - 1] > cprev) jj--;
    while (jj <= 256 && s_p[jj] <= cprev) jj++;
    float r = run;
    for (int k = 0; k < emax; k++) {
      float cu_uns = (k == emax - 1) ? incl : (r + sA[k]);
      r = cu_uns;
      float cu = fminf(cu_uns * inv, 1.0f);
      float tq = tl[k + 1];
      while (jj <= 256 && s_p[jj] <= cu) { s_q[jj] = tq; jj++; }
    }
    if (tid == 0) s_q[0] = tl[0];                    // p[0]=0 -> cdf idx 0
    if (tid == TPB - 1) {                            // p[j] > cdf_max -> idx NT-1
      float tq = tl[EPT - 1];
      while (jj <= 256) { s_q[jj] = tq; jj++; }
    }
  }
  __syncthreads();                                   // B2

  // ================= spline rhs + banded solve =================
  // load f row now to hide global latency under the solve
  const float* frow = f + (size_t)row * NT_;
  float fv[EPT + 1];
  {
    const float4 a = *reinterpret_cast<const float4*>(frow + base);
    const float4 b = *reinterpret_cast<const float4*>(frow + base + 4);
    fv[0] = a.x; fv[1] = a.y; fv[2] = a.z; fv[3] = a.w;
    fv[4] = b.x; fv[5] = b.y; fv[6] = b.z; fv[7] = b.w;
  }
  fv[EPT] = (tid < TPB - 1) ? frow[base + EPT] : 0.0f;

  if (tid < 255) {
    float h0 = s_p[tid + 1] - s_p[tid], h1 = s_p[tid + 2] - s_p[tid + 1];
    float sl0 = (s_q[tid + 1] - s_q[tid]) / h0;
    float sl1 = (s_q[tid + 2] - s_q[tid + 1]) / h1;
    s_rhs[BW + tid] = 6.0f * (sl1 - sl0);
  }
  if (tid < BW) s_rhs[tid] = 0.0f;
  if (tid >= TPB - BW) s_rhs[tid + (2 * BW - 1)] = 0.0f;  // 271..286
  __syncthreads();                                   // B3

  float Mreg = 0.0f;
  if (tid < 255) {
    #pragma unroll 11
    for (int dd = 0; dd < BD; dd++)
      Mreg += bandS[dd * 256 + tid] * s_rhs[tid + dd];
  }
  if (tid < 255) s_M[tid + 1] = Mreg;
  if (tid == 0) { s_M[0] = 0.0f; s_M[256] = 0.0f; }
  __syncthreads();                                   // B4

  {
    float h = s_p[tid + 1] - s_p[tid];
    float Mi = s_M[tid], Mi1 = s_M[tid + 1];
    float sl = (s_q[tid + 1] - s_q[tid]) / h;
    s_b[tid] = sl - h * (2.0f * Mi + Mi1) * (1.0f / 6.0f);
    s_c[tid] = 0.5f * Mi;
    s_d[tid] = (Mi1 - Mi) / (6.0f * h);
  }
  __syncthreads();                                   // B5

  // ================= Phase B: f^2 -> F scan -> spline eval + weighted trapz =========
  float sB[EPT];
  float ep2 = 0.0f;
  for (int k = 0; k < emax; k++) {
    sB[k] = fv[k] * fv[k] + fv[k + 1] * fv[k + 1];
    ep2 += sB[k];
  }
  if (emax < EPT) sB[EPT - 1] = 0.0f;
  float v2 = ep2;
  #pragma unroll
  for (int off = 1; off < 64; off <<= 1) {
    float w = __shfl_up(v2, off, 64);
    if (lane >= off) v2 += w;
  }
  float excl2 = __shfl_up(v2, 1, 64);
  if (lane == 0) excl2 = 0.0f;
  if (lane == 63) s_wf[wid] = v2;
  __syncthreads();                                   // B6
  float woff2 = 0.0f, tot2 = 0.0f;
  #pragma unroll
  for (int w = 0; w < 4; w++) {
    float sw = s_wf[w];
    if (w < wid) woff2 += sw;
    tot2 += sw;
  }
  float run2 = woff2 + excl2;
  float inv2 = 1.0f / tot2;

  double wsum = 0.0;
  {
    float r2 = run2;
    #pragma unroll
    for (int k = 0; k < EPT; k++) {
      if (k > 0) r2 += sB[k - 1];
      float F = r2 * inv2;
      int lo = (int)(F * 256.0f) + 1;
      if (lo < 0) lo = 0; if (lo > 256) lo = 256;
      while (lo > 0 && s_p[lo - 1] >= F) lo--;
      while (lo < 257 && s_p[lo] < F) lo++;
      int idx = lo - 1;
      if (idx < 0) idx = 0; if (idx > 255) idx = 255;
      float frac = F - s_p[idx];
      float val = s_q[idx] + frac * (s_b[idx] + frac * (s_c[idx] + frac * s_d[idx]));
      float diff = tl[k] - val;
      float wv = diff * diff * fv[k];
      if (tid == 0 && k == 0) s_misc[0] = (double)wv;
      if (tid == TPB - 1 && k == EPT - 1) s_misc[1] = (double)wv;
      wsum += (double)wv;
    }
  }
  double rv = wsum;
  #pragma unroll
  for (int off = 32; off >= 1; off >>= 1) rv += shfl_down_f64(rv, off);
  if (lane == 0) s_wd[wid] = rv;
  __syncthreads();                                   // B7
  if (tid == 0) {
    double totw = s_wd[0] + s_wd[1] + s_wd[2] + s_wd[3];
    row_out[row] = (totw - 0.5 * (s_misc[0] + s_misc[1])) * dx;
  }
}

__global__ void w2_reduce(const double* __restrict__ row_out, int ntr,
                          float* __restrict__ out) {
  __shared__ double s[TPB];
  int tid = threadIdx.x;
  double v = 0.0;
  for (int i = tid; i < ntr; i += TPB) v += row_out[i];
  s[tid] = v; __syncthreads();
  for (int off = TPB / 2; off > 0; off >>= 1) {
    if (tid < off) s[tid] += s[tid + off];
    __syncthreads();
  }
  if (tid == 0) out[0] = (float)s[0];
}

extern "C" void kernel_launch(void* const* d_in, const int* in_sizes, int n_in,
                              void* d_out, int out_size, void* d_ws, size_t ws_size,
                              hipStream_t stream) {
  const float* f   = (const float*)d_in[0];
  const float* obs = (const float*)d_in[1];
  const float* t   = (const float*)d_in[2];
  const float* p   = (const float*)d_in[3];
  int nt = in_sizes[2];          // 2048
  int ntr = in_sizes[0] / nt;    // 4096

  float* bandS = (float*)d_ws;
  double* rows = (double*)((char*)d_ws + BAND_BYTES);

  hipLaunchKernelGGL(w2_setup, dim3(1), dim3(256), 0, stream, p, bandS);
  hipLaunchKernelGGL(w2_main, dim3(ntr), dim3(TPB), 0, stream,
                     f, obs, t, p, bandS, rows);
  hipLaunchKernelGGL(w2_reduce, dim3(1), dim3(TPB), 0, stream,
                     rows, ntr, (float*)d_out);
}